// Round 1
// baseline (81.723 us; speedup 1.0000x reference)
//
#include <hip/hip_runtime.h>
#include <math.h>

#define B_    4
#define TDEC  512
#define TENC  1024
#define H_    128
#define D_TILE 4
#define NT    512

// Kernel 1: TET[b][h][e] = tanh(enc[b][e][h])  (tiled transpose + tanh)
__global__ __launch_bounds__(256) void tet_kernel(const float* __restrict__ enc,
                                                  float* __restrict__ tet) {
    __shared__ float tile[32][33];
    const int e0 = blockIdx.x * 32, h0 = blockIdx.y * 32, b = blockIdx.z;
    const int x = threadIdx.x, y = threadIdx.y;
    const float* ep = enc + (size_t)b * TENC * H_;
    #pragma unroll
    for (int j = 0; j < 32; j += 8)
        tile[y + j][x] = ep[(size_t)(e0 + y + j) * H_ + h0 + x];
    __syncthreads();
    float* tp = tet + (size_t)b * H_ * TENC;
    #pragma unroll
    for (int j = 0; j < 32; j += 8)
        tp[(size_t)(h0 + y + j) * TENC + e0 + x] = tanhf(tile[x][y + j]);
}

// Kernel 2: one block per (b, tile of D_TILE decoder rows)
__global__ __launch_bounds__(NT) void attn_kernel(
    const float* __restrict__ dec, const float* __restrict__ enc,
    const float* __restrict__ Ww, const float* __restrict__ Wb,
    const float* __restrict__ Vw, const float* __restrict__ Vb,
    const float* __restrict__ tet, float* __restrict__ out)
{
    __shared__ float Vs[H_];
    __shared__ float decs[D_TILE][H_];
    __shared__ float TDs[D_TILE][H_];
    __shared__ float sc[D_TILE][TENC];
    __shared__ float2 part[8][D_TILE][H_ / 2];
    __shared__ float rsum[D_TILE];

    const int t = threadIdx.x;
    const int blk = blockIdx.x;
    const int b = blk >> 7;                 // blk / (TDEC/D_TILE)
    const int d0 = (blk & 127) * D_TILE;

    if (t < H_) Vs[t] = Vw[t];
    {
        const int d = t >> 7, h = t & 127;
        decs[d][h] = dec[(size_t)((b * TDEC) + d0 + d) * H_ + h];
    }
    __syncthreads();

    // --- Phase A: dec_t = decs @ Ww^T + Wb, tanh -> TDs ---
    // wave w: d = w>>1, k-half = (w&1)*64; lanes split h (coalesced W reads)
    {
        const int w = t >> 6, lane = t & 63;
        const int d = w >> 1, kbase = (w & 1) * 64;
        const float dx = decs[d][2 * lane], dy = decs[d][2 * lane + 1];
        float myv = 0.f;
        for (int i = 0; i < 64; ++i) {
            const int k = kbase + i;
            const float2 wv = *(const float2*)(Ww + (size_t)k * H_ + 2 * lane);
            float p = fmaf(wv.y, dy, wv.x * dx);
            #pragma unroll
            for (int off = 32; off; off >>= 1) p += __shfl_xor(p, off);
            if (lane == i) myv = p;
        }
        const int k = kbase + lane;
        TDs[d][k] = tanhf(myv + Wb[k]);
    }
    __syncthreads();

    // --- Phase B: scores via tanh-addition identity ---
    // tanh(a+b) = (ta+tb)/(1+ta*tb); fold V:  V*(ta+tb) = fma(V, tb, V*ta)
    const float vb = Vb[0];
    float acc[2][D_TILE];
    #pragma unroll
    for (int g = 0; g < 2; ++g)
        #pragma unroll
        for (int d = 0; d < D_TILE; ++d) acc[g][d] = 0.f;

    const float* tb = tet + (size_t)b * H_ * TENC;
    for (int h = 0; h < H_; ++h) {
        const float v = Vs[h];
        const float td0 = TDs[0][h], td1 = TDs[1][h];
        const float td2 = TDs[2][h], td3 = TDs[3][h];
        const float vt0 = v * td0, vt1 = v * td1, vt2 = v * td2, vt3 = v * td3;
        const float* ter = tb + (size_t)h * TENC + t;
        #pragma unroll
        for (int g = 0; g < 2; ++g) {
            const float te = ter[g * NT];
            const float r0 = __builtin_amdgcn_rcpf(fmaf(td0, te, 1.f));
            acc[g][0] = fmaf(fmaf(v, te, vt0), r0, acc[g][0]);
            const float r1 = __builtin_amdgcn_rcpf(fmaf(td1, te, 1.f));
            acc[g][1] = fmaf(fmaf(v, te, vt1), r1, acc[g][1]);
            const float r2 = __builtin_amdgcn_rcpf(fmaf(td2, te, 1.f));
            acc[g][2] = fmaf(fmaf(v, te, vt2), r2, acc[g][2]);
            const float r3 = __builtin_amdgcn_rcpf(fmaf(td3, te, 1.f));
            acc[g][3] = fmaf(fmaf(v, te, vt3), r3, acc[g][3]);
        }
    }
    #pragma unroll
    for (int g = 0; g < 2; ++g)
        #pragma unroll
        for (int d = 0; d < D_TILE; ++d)
            sc[d][t + g * NT] = acc[g][d] + vb;
    __syncthreads();

    // --- Phase C: softmax per d-row (unnormalized; 1/sum folded at end) ---
    {
        const int w = t >> 6, lane = t & 63;
        if (w < D_TILE) {
            const int d = w;
            float m = -3.0e38f;
            #pragma unroll
            for (int i = 0; i < TENC / 64; ++i) m = fmaxf(m, sc[d][lane + i * 64]);
            #pragma unroll
            for (int off = 32; off; off >>= 1) m = fmaxf(m, __shfl_xor(m, off));
            float s = 0.f;
            #pragma unroll
            for (int i = 0; i < TENC / 64; ++i) {
                const float p = __expf(sc[d][lane + i * 64] - m);
                sc[d][lane + i * 64] = p;
                s += p;
            }
            #pragma unroll
            for (int off = 32; off; off >>= 1) s += __shfl_xor(s, off);
            if (lane == 0) rsum[d] = s;
        }
    }
    __syncthreads();

    // --- Phase D: context = (p @ enc) / sum ---
    {
        const int h2 = t & 63, q = t >> 6;
        float2 cacc[D_TILE];
        #pragma unroll
        for (int d = 0; d < D_TILE; ++d) cacc[d] = make_float2(0.f, 0.f);
        const float* eb = enc + (size_t)b * TENC * H_;
        const int e0 = q * (TENC / 8);
        for (int e = e0; e < e0 + TENC / 8; ++e) {
            const float2 ev = *(const float2*)(eb + (size_t)e * H_ + 2 * h2);
            #pragma unroll
            for (int d = 0; d < D_TILE; ++d) {
                const float p = sc[d][e];
                cacc[d].x = fmaf(p, ev.x, cacc[d].x);
                cacc[d].y = fmaf(p, ev.y, cacc[d].y);
            }
        }
        #pragma unroll
        for (int d = 0; d < D_TILE; ++d) part[q][d][h2] = cacc[d];
    }
    __syncthreads();

    if (t < 256) {
        const int d = t >> 6, h2 = t & 63;
        float2 s = make_float2(0.f, 0.f);
        #pragma unroll
        for (int q = 0; q < 8; ++q) {
            const float2 pp = part[q][d][h2];
            s.x += pp.x; s.y += pp.y;
        }
        const float rinv = __builtin_amdgcn_rcpf(rsum[d]);
        s.x *= rinv; s.y *= rinv;
        *(float2*)(out + (size_t)((b * TDEC) + d0 + d) * H_ + 2 * h2) = s;
    }
}

extern "C" void kernel_launch(void* const* d_in, const int* in_sizes, int n_in,
                              void* d_out, int out_size, void* d_ws, size_t ws_size,
                              hipStream_t stream) {
    const float* dec = (const float*)d_in[0];
    const float* enc = (const float*)d_in[1];
    const float* Ww  = (const float*)d_in[2];
    const float* Wb  = (const float*)d_in[3];
    const float* Vw  = (const float*)d_in[4];
    const float* Vb  = (const float*)d_in[5];
    float* out = (float*)d_out;
    float* tet = (float*)d_ws;  // B_*H_*TENC floats = 2 MB of scratch

    tet_kernel<<<dim3(TENC / 32, H_ / 32, B_), dim3(32, 8), 0, stream>>>(enc, tet);
    attn_kernel<<<dim3(B_ * TDEC / D_TILE), dim3(NT), 0, stream>>>(
        dec, enc, Ww, Wb, Vw, Vb, tet, out);
}

// Round 2
// 70.297 us; speedup vs baseline: 1.1625x; 1.1625x over previous
//
#include <hip/hip_runtime.h>
#include <math.h>

#define B_    4
#define TDEC  512
#define TENC  1024
#define H_    128
#define D_TILE 4
#define NT    512

union F4 { float4 v; float f[4]; };

__device__ __forceinline__ float ftanh(float x) {
    // tanh(x) = 1 - 2/(e^{2x}+1); exp at quarter rate, rcp ~1ulp
    float e = __expf(2.f * x);
    return fmaf(-2.f, __builtin_amdgcn_rcpf(e + 1.f), 1.f);
}

// prep: z<4 -> tet[b][h][e] = tanh(enc[b][e][h]) ; z==4 -> WwT[h][k] = Ww[k][h]
__global__ __launch_bounds__(256) void prep_kernel(const float* __restrict__ enc,
                                                   const float* __restrict__ Ww,
                                                   float* __restrict__ tet,
                                                   float* __restrict__ wwt,
                                                   int use_wwt) {
    __shared__ float tile[32][33];
    const int tx = threadIdx.x, ty = threadIdx.y;
    const int z = blockIdx.z;
    if (z < 4) {
        const int e0 = blockIdx.x * 32, h0 = blockIdx.y * 32, b = z;
        const float* ep = enc + (size_t)b * TENC * H_;
        #pragma unroll
        for (int j = 0; j < 32; j += 8)
            tile[ty + j][tx] = ep[(size_t)(e0 + ty + j) * H_ + h0 + tx];
        __syncthreads();
        float* tp = tet + (size_t)b * H_ * TENC;
        #pragma unroll
        for (int j = 0; j < 32; j += 8)
            tp[(size_t)(h0 + ty + j) * TENC + e0 + tx] = ftanh(tile[tx][ty + j]);
    } else {
        if (!use_wwt || blockIdx.y != 0 || blockIdx.x >= 16) return;
        const int k0 = (blockIdx.x & 3) * 32, h0 = (blockIdx.x >> 2) * 32;
        #pragma unroll
        for (int j = 0; j < 32; j += 8)
            tile[ty + j][tx] = Ww[(size_t)(k0 + ty + j) * H_ + h0 + tx];
        __syncthreads();
        #pragma unroll
        for (int j = 0; j < 32; j += 8)
            wwt[(size_t)(h0 + ty + j) * H_ + k0 + tx] = tile[tx][ty + j];
    }
}

__global__ __launch_bounds__(NT) void attn_kernel(
    const float* __restrict__ dec, const float* __restrict__ enc,
    const float* __restrict__ Ww, const float* __restrict__ Wb,
    const float* __restrict__ Vw,
    const float* __restrict__ tet, const float* __restrict__ wwt,
    int use_wwt, float* __restrict__ out)
{
    __shared__ float Vs[H_];
    __shared__ float decs[D_TILE][H_];
    __shared__ float TDs[D_TILE][H_];
    __shared__ float sc[2][D_TILE][TENC];
    __shared__ float2 part[8][D_TILE][H_ / 2];
    __shared__ float rsum[D_TILE];

    const int t = threadIdx.x;
    const int blk = blockIdx.x;
    const int b = blk >> 7;
    const int d0 = (blk & 127) * D_TILE;

    if (t < H_) Vs[t] = Vw[t];
    {
        const int d = t >> 7, h = t & 127;
        decs[d][h] = dec[(size_t)((b * TDEC) + d0 + d) * H_ + h];
    }
    __syncthreads();

    // --- Phase A: TDs = tanh(decs @ Ww^T + Wb) ---
    if (use_wwt) {
        const int d = t >> 7, k = t & 127;
        float s = 0.f;
        #pragma unroll 4
        for (int h = 0; h < H_; h += 4) {
            const float4 dv = *(const float4*)&decs[d][h];
            s = fmaf(dv.x, wwt[(size_t)(h + 0) * H_ + k], s);
            s = fmaf(dv.y, wwt[(size_t)(h + 1) * H_ + k], s);
            s = fmaf(dv.z, wwt[(size_t)(h + 2) * H_ + k], s);
            s = fmaf(dv.w, wwt[(size_t)(h + 3) * H_ + k], s);
        }
        TDs[d][k] = ftanh(s + Wb[k]);
    } else {
        const int w = t >> 6, lane = t & 63;
        const int d = w >> 1, kbase = (w & 1) * 64;
        const float dx = decs[d][2 * lane], dy = decs[d][2 * lane + 1];
        float myv = 0.f;
        for (int i = 0; i < 64; ++i) {
            const int k = kbase + i;
            const float2 wv = *(const float2*)(Ww + (size_t)k * H_ + 2 * lane);
            float p = fmaf(wv.y, dy, wv.x * dx);
            #pragma unroll
            for (int off = 32; off; off >>= 1) p += __shfl_xor(p, off);
            if (lane == i) myv = p;
        }
        const int k = kbase + lane;
        TDs[d][k] = ftanh(myv + Wb[k]);
    }
    __syncthreads();

    // --- Phase B: scores via tanh identity, h split 2-way, float4 over e ---
    {
        const int hg = t >> 8;          // 0 or 1 -> h in [hg*64, hg*64+64)
        const int tid = t & 255;
        const int e0 = tid * 4;
        F4 accu[4];
        #pragma unroll
        for (int d = 0; d < 4; ++d) accu[d].v = make_float4(0.f, 0.f, 0.f, 0.f);
        const float* tb = tet + (size_t)b * H_ * TENC + (size_t)(hg * 64) * TENC;
        const float* vbase = &Vs[hg * 64];
        const float* tdbase = &TDs[0][hg * 64];

        #pragma unroll 2
        for (int hb = 0; hb < 64; hb += 4) {
            F4 v4; v4.v = *(const float4*)(vbase + hb);
            F4 td4[4];
            #pragma unroll
            for (int d = 0; d < 4; ++d)
                td4[d].v = *(const float4*)(tdbase + (size_t)d * H_ + hb);
            #pragma unroll
            for (int j = 0; j < 4; ++j) {
                F4 te; te.v = *(const float4*)(tb + (size_t)(hb + j) * TENC + e0);
                const float v = v4.f[j];
                #pragma unroll
                for (int d = 0; d < 4; ++d) {
                    const float td = td4[d].f[j];
                    const float vt = v * td;
                    #pragma unroll
                    for (int c = 0; c < 4; ++c) {
                        const float den = fmaf(td, te.f[c], 1.f);
                        const float r = __builtin_amdgcn_rcpf(den);
                        const float num = fmaf(v, te.f[c], vt);
                        accu[d].f[c] = fmaf(num, r, accu[d].f[c]);
                    }
                }
            }
        }
        #pragma unroll
        for (int d = 0; d < 4; ++d)
            *(float4*)&sc[hg][d][e0] = accu[d].v;
    }
    __syncthreads();

    // --- Phase C: merge h-halves + softmax per d-row (unnormalized) ---
    if (t < 256) {
        const int d = t >> 6, lane = t & 63;
        float vals[16];
        float m = -3.0e38f;
        #pragma unroll
        for (int i = 0; i < 16; ++i) {
            const float p = sc[0][d][lane + 64 * i] + sc[1][d][lane + 64 * i];
            vals[i] = p;
            m = fmaxf(m, p);
        }
        #pragma unroll
        for (int off = 32; off; off >>= 1) m = fmaxf(m, __shfl_xor(m, off));
        float s = 0.f;
        #pragma unroll
        for (int i = 0; i < 16; ++i) {
            const float p = __expf(vals[i] - m);
            sc[0][d][lane + 64 * i] = p;
            s += p;
        }
        #pragma unroll
        for (int off = 32; off; off >>= 1) s += __shfl_xor(s, off);
        if (lane == 0) rsum[d] = s;
    }
    __syncthreads();

    // --- Phase D: context = (p @ enc) / sum ---
    {
        const int h2 = t & 63, q = t >> 6;
        float2 cacc[D_TILE];
        #pragma unroll
        for (int d = 0; d < 4; ++d) cacc[d] = make_float2(0.f, 0.f);
        const float* eb = enc + (size_t)b * TENC * H_;
        const int e0 = q * (TENC / 8);
        for (int e = e0; e < e0 + TENC / 8; ++e) {
            const float2 ev = *(const float2*)(eb + (size_t)e * H_ + 2 * h2);
            #pragma unroll
            for (int d = 0; d < 4; ++d) {
                const float p = sc[0][d][e];
                cacc[d].x = fmaf(p, ev.x, cacc[d].x);
                cacc[d].y = fmaf(p, ev.y, cacc[d].y);
            }
        }
        #pragma unroll
        for (int d = 0; d < 4; ++d) part[q][d][h2] = cacc[d];
    }
    __syncthreads();

    if (t < 256) {
        const int d = t >> 6, h2 = t & 63;
        float2 s = make_float2(0.f, 0.f);
        #pragma unroll
        for (int q = 0; q < 8; ++q) {
            const float2 pp = part[q][d][h2];
            s.x += pp.x; s.y += pp.y;
        }
        const float rinv = __builtin_amdgcn_rcpf(rsum[d]);
        s.x *= rinv; s.y *= rinv;
        *(float2*)(out + (size_t)((b * TDEC) + d0 + d) * H_ + 2 * h2) = s;
    }
}

extern "C" void kernel_launch(void* const* d_in, const int* in_sizes, int n_in,
                              void* d_out, int out_size, void* d_ws, size_t ws_size,
                              hipStream_t stream) {
    const float* dec = (const float*)d_in[0];
    const float* enc = (const float*)d_in[1];
    const float* Ww  = (const float*)d_in[2];
    const float* Wb  = (const float*)d_in[3];
    const float* Vw  = (const float*)d_in[4];
    float* out = (float*)d_out;

    const size_t tet_bytes = (size_t)B_ * H_ * TENC * sizeof(float);
    const size_t wwt_bytes = (size_t)H_ * H_ * sizeof(float);
    float* tet = (float*)d_ws;
    float* wwt = (float*)((char*)d_ws + tet_bytes);
    const int use_wwt = (ws_size >= tet_bytes + wwt_bytes) ? 1 : 0;

    prep_kernel<<<dim3(TENC / 32, H_ / 32, B_ + 1), dim3(32, 8), 0, stream>>>(
        enc, Ww, tet, wwt, use_wwt);
    attn_kernel<<<dim3(B_ * TDEC / D_TILE), dim3(NT), 0, stream>>>(
        dec, enc, Ww, Wb, Vw, tet, wwt, use_wwt, out);
}

// Round 3
// 62.396 us; speedup vs baseline: 1.3097x; 1.1266x over previous
//
#include <hip/hip_runtime.h>
#include <math.h>
#include <stdint.h>

#define B_    4
#define TDEC  512
#define TENC  1024
#define H_    128
#define D_TILE 4
#define NT    512
#define NG    (H_ / 4)   // 32 groups of 4 h-planes

union F4 { float4 v; float f[4]; };
union F2 { float2 v; float f[2]; };

__device__ __forceinline__ float ftanh(float x) {
    // tanh(x) = 1 - 2/(e^{2x}+1)
    float e = __expf(2.f * x);
    return fmaf(-2.f, __builtin_amdgcn_rcpf(e + 1.f), 1.f);
}

// prep: z<4 -> tet[b][h][e] = tanh(enc[b][e][h]) ; z==4 -> WwT[h][k] = Ww[k][h]
__global__ __launch_bounds__(256) void prep_kernel(const float* __restrict__ enc,
                                                   const float* __restrict__ Ww,
                                                   float* __restrict__ tet,
                                                   float* __restrict__ wwt,
                                                   int use_wwt) {
    __shared__ float tile[32][33];
    const int tx = threadIdx.x, ty = threadIdx.y;
    const int z = blockIdx.z;
    if (z < 4) {
        const int e0 = blockIdx.x * 32, h0 = blockIdx.y * 32, b = z;
        const float* ep = enc + (size_t)b * TENC * H_;
        #pragma unroll
        for (int j = 0; j < 32; j += 8)
            tile[ty + j][tx] = ep[(size_t)(e0 + ty + j) * H_ + h0 + tx];
        __syncthreads();
        float* tp = tet + (size_t)b * H_ * TENC;
        #pragma unroll
        for (int j = 0; j < 32; j += 8)
            tp[(size_t)(h0 + ty + j) * TENC + e0 + tx] = ftanh(tile[tx][ty + j]);
    } else {
        if (!use_wwt || blockIdx.y != 0 || blockIdx.x >= 16) return;
        const int k0 = (blockIdx.x & 3) * 32, h0 = (blockIdx.x >> 2) * 32;
        #pragma unroll
        for (int j = 0; j < 32; j += 8)
            tile[ty + j][tx] = Ww[(size_t)(k0 + ty + j) * H_ + h0 + tx];
        __syncthreads();
        #pragma unroll
        for (int j = 0; j < 32; j += 8)
            wwt[(size_t)(h0 + ty + j) * H_ + k0 + tx] = tile[tx][ty + j];
    }
}

#if defined(__has_builtin)
#if __has_builtin(__builtin_amdgcn_global_load_lds)
#define HAVE_DMA 1
#endif
#endif

#ifdef HAVE_DMA
// Stage 16KB (4 h-rows of te) into tebuf[bufi]; wave w covers 2KB via 2 DMA insts.
// LDS dest is wave-uniform base + lane*16 (HW); global src is per-lane.
#define STAGE(bufi, g) do {                                                          \
    const float* gs_ = tetb + (size_t)(g) * (4 * TENC) + w * 512;                    \
    float* ls_ = &tebuf[bufi][0][0] + w * 512;                                       \
    __builtin_amdgcn_global_load_lds(                                                \
        (__attribute__((address_space(1))) void*)(gs_ + lane * 4),                   \
        (__attribute__((address_space(3))) void*)ls_, 16, 0, 0);                     \
    __builtin_amdgcn_global_load_lds(                                                \
        (__attribute__((address_space(1))) void*)(gs_ + 256 + lane * 4),             \
        (__attribute__((address_space(3))) void*)(ls_ + 256), 16, 0, 0);             \
} while (0)
#else
#define STAGE(bufi, g) do {                                                          \
    const float* gs_ = tetb + (size_t)(g) * (4 * TENC) + w * 512 + lane * 4;         \
    float* ls_ = &tebuf[bufi][0][0] + w * 512 + lane * 4;                            \
    *(float4*)ls_ = *(const float4*)gs_;                                             \
    *(float4*)(ls_ + 256) = *(const float4*)(gs_ + 256);                             \
} while (0)
#endif

__global__ __launch_bounds__(NT) void attn_kernel(
    const float* __restrict__ dec, const float* __restrict__ enc,
    const float* __restrict__ Ww, const float* __restrict__ Wb,
    const float* __restrict__ Vw,
    const float* __restrict__ tet, const float* __restrict__ wwt,
    int use_wwt, float* __restrict__ out)
{
    __shared__ float Vs[H_];
    __shared__ float decs[D_TILE][H_];
    __shared__ float TDs[D_TILE][H_];
    __shared__ float sc[D_TILE][TENC];
    __shared__ float tebuf[2][4][TENC];
    __shared__ float2 part[8][D_TILE][H_ / 2];
    __shared__ float rsum[D_TILE];

    const int t = threadIdx.x;
    const int w = t >> 6, lane = t & 63;
    const int blk = blockIdx.x;
    const int b = blk >> 7;
    const int d0 = (blk & 127) * D_TILE;

    const float* tetb = tet + (size_t)b * H_ * TENC;

    // Prefetch te groups 0,1 under the setup loads + matvec.
    STAGE(0, 0);
    STAGE(1, 1);

    if (t < H_) Vs[t] = Vw[t];
    {
        const int d = t >> 7, h = t & 127;
        decs[d][h] = dec[(size_t)((b * TDEC) + d0 + d) * H_ + h];
    }
    __syncthreads();

    // --- Phase A: TDs = tanh(decs @ Ww^T + Wb) ---
    if (use_wwt) {
        const int d = t >> 7, k = t & 127;
        float s = 0.f;
        #pragma unroll 4
        for (int h = 0; h < H_; h += 4) {
            const float4 dv = *(const float4*)&decs[d][h];
            s = fmaf(dv.x, wwt[(size_t)(h + 0) * H_ + k], s);
            s = fmaf(dv.y, wwt[(size_t)(h + 1) * H_ + k], s);
            s = fmaf(dv.z, wwt[(size_t)(h + 2) * H_ + k], s);
            s = fmaf(dv.w, wwt[(size_t)(h + 3) * H_ + k], s);
        }
        TDs[d][k] = ftanh(s + Wb[k]);
    } else {
        const int d = w >> 1, kbase = (w & 1) * 64;
        const float dx = decs[d][2 * lane], dy = decs[d][2 * lane + 1];
        float myv = 0.f;
        for (int i = 0; i < 64; ++i) {
            const int k = kbase + i;
            const float2 wv = *(const float2*)(Ww + (size_t)k * H_ + 2 * lane);
            float p = fmaf(wv.y, dy, wv.x * dx);
            #pragma unroll
            for (int off = 32; off; off >>= 1) p += __shfl_xor(p, off);
            if (lane == i) myv = p;
        }
        const int k = kbase + lane;
        TDs[d][k] = ftanh(myv + Wb[k]);
    }
    __syncthreads();   // also drains STAGE(0)/STAGE(1)

    // --- Phase B: scores via tanh identity + 4-term fraction combining ---
    // term(d,e,h) = V_h*(td+te)/(1+td*te); combine 4 h into one rcp:
    // sum_i x_i/p_i = ((x0 p1 + x1 p0) p2 p3 + (x2 p3 + x3 p2) p0 p1) / (p0 p1 p2 p3)
    F2 acc[D_TILE];
    #pragma unroll
    for (int d = 0; d < D_TILE; ++d) acc[d].v = make_float2(0.f, 0.f);

    for (int g = 0; g < NG; ++g) {
        const int bi = g & 1;
        F4 v4, td[D_TILE];
        v4.v = *(const float4*)&Vs[4 * g];
        #pragma unroll
        for (int d = 0; d < D_TILE; ++d) td[d].v = *(const float4*)&TDs[d][4 * g];
        F2 te[4];
        #pragma unroll
        for (int hh = 0; hh < 4; ++hh)
            te[hh].v = *(const float2*)&tebuf[bi][hh][2 * t];

        #pragma unroll
        for (int d = 0; d < D_TILE; ++d) {
            const float q0 = v4.f[0] * td[d].f[0];
            const float q1 = v4.f[1] * td[d].f[1];
            const float q2 = v4.f[2] * td[d].f[2];
            const float q3 = v4.f[3] * td[d].f[3];
            #pragma unroll
            for (int c = 0; c < 2; ++c) {
                const float t0 = te[0].f[c], t1 = te[1].f[c];
                const float t2 = te[2].f[c], t3 = te[3].f[c];
                const float p0 = fmaf(td[d].f[0], t0, 1.f);
                const float p1 = fmaf(td[d].f[1], t1, 1.f);
                const float p2 = fmaf(td[d].f[2], t2, 1.f);
                const float p3 = fmaf(td[d].f[3], t3, 1.f);
                const float x0 = fmaf(v4.f[0], t0, q0);
                const float x1 = fmaf(v4.f[1], t1, q1);
                const float x2 = fmaf(v4.f[2], t2, q2);
                const float x3 = fmaf(v4.f[3], t3, q3);
                const float p01 = p0 * p1, p23 = p2 * p3;
                const float u = fmaf(x1, p0, x0 * p1);
                const float z = fmaf(x3, p2, x2 * p3);
                const float num = fmaf(z, p01, u * p23);
                const float den = p01 * p23;
                acc[d].f[c] = fmaf(num, __builtin_amdgcn_rcpf(den), acc[d].f[c]);
            }
        }
        __syncthreads();                 // all waves done reading tebuf[bi]
        if (g + 2 < NG) STAGE(bi, g + 2);  // refill it for group g+2
    }

    #pragma unroll
    for (int d = 0; d < D_TILE; ++d)
        *(float2*)&sc[d][2 * t] = acc[d].v;
    __syncthreads();

    // --- Phase C: softmax per d-row (unnormalized; 1/sum folded at end) ---
    if (t < 256) {
        const int d = t >> 6, ln = t & 63;
        float vals[16];
        float m = -3.0e38f;
        #pragma unroll
        for (int i = 0; i < 16; ++i) {
            const float p = sc[d][ln + 64 * i];
            vals[i] = p;
            m = fmaxf(m, p);
        }
        #pragma unroll
        for (int off = 32; off; off >>= 1) m = fmaxf(m, __shfl_xor(m, off));
        float s = 0.f;
        #pragma unroll
        for (int i = 0; i < 16; ++i) {
            const float p = __expf(vals[i] - m);
            sc[d][ln + 64 * i] = p;
            s += p;
        }
        #pragma unroll
        for (int off = 32; off; off >>= 1) s += __shfl_xor(s, off);
        if (ln == 0) rsum[d] = s;
    }
    __syncthreads();

    // --- Phase D: context = (p @ enc) / sum ---
    {
        const int h2 = t & 63, q = t >> 6;
        float2 cacc[D_TILE];
        #pragma unroll
        for (int d = 0; d < D_TILE; ++d) cacc[d] = make_float2(0.f, 0.f);
        const float* eb = enc + (size_t)b * TENC * H_;
        const int e0 = q * (TENC / 8);
        for (int e = e0; e < e0 + TENC / 8; ++e) {
            const float2 ev = *(const float2*)(eb + (size_t)e * H_ + 2 * h2);
            #pragma unroll
            for (int d = 0; d < D_TILE; ++d) {
                const float p = sc[d][e];
                cacc[d].x = fmaf(p, ev.x, cacc[d].x);
                cacc[d].y = fmaf(p, ev.y, cacc[d].y);
            }
        }
        #pragma unroll
        for (int d = 0; d < D_TILE; ++d) part[q][d][h2] = cacc[d];
    }
    __syncthreads();

    if (t < 256) {
        const int d = t >> 6, h2 = t & 63;
        float2 s = make_float2(0.f, 0.f);
        #pragma unroll
        for (int q = 0; q < 8; ++q) {
            const float2 pp = part[q][d][h2];
            s.x += pp.x; s.y += pp.y;
        }
        const float rinv = __builtin_amdgcn_rcpf(rsum[d]);
        s.x *= rinv; s.y *= rinv;
        *(float2*)(out + (size_t)((b * TDEC) + d0 + d) * H_ + 2 * h2) = s;
    }
}

extern "C" void kernel_launch(void* const* d_in, const int* in_sizes, int n_in,
                              void* d_out, int out_size, void* d_ws, size_t ws_size,
                              hipStream_t stream) {
    const float* dec = (const float*)d_in[0];
    const float* enc = (const float*)d_in[1];
    const float* Ww  = (const float*)d_in[2];
    const float* Wb  = (const float*)d_in[3];
    const float* Vw  = (const float*)d_in[4];
    float* out = (float*)d_out;

    const size_t tet_bytes = (size_t)B_ * H_ * TENC * sizeof(float);
    const size_t wwt_bytes = (size_t)H_ * H_ * sizeof(float);
    float* tet = (float*)d_ws;
    float* wwt = (float*)((char*)d_ws + tet_bytes);
    const int use_wwt = (ws_size >= tet_bytes + wwt_bytes) ? 1 : 0;

    prep_kernel<<<dim3(TENC / 32, H_ / 32, B_ + 1), dim3(32, 8), 0, stream>>>(
        enc, Ww, tet, wwt, use_wwt);
    attn_kernel<<<dim3(B_ * TDEC / D_TILE), dim3(NT), 0, stream>>>(
        dec, enc, Ww, Wb, Vw, tet, wwt, use_wwt, out);
}